// Round 1
// baseline (399.046 us; speedup 1.0000x reference)
//
#include <hip/hip_runtime.h>
#include <stdint.h>

#define M_DIM 16384
#define K_DIM 1024
#define N_DIM 4096
#define BM 128
#define BN 128
#define BK 32
#define LDSP 40   // bf16 per LDS row: 32 + 8 pad -> 80B stride, <=2-way bank alias (free)

typedef __bf16 bf16;
typedef __attribute__((ext_vector_type(8))) __bf16 bf16x8;
typedef __attribute__((ext_vector_type(4))) float f32x4;

// round-to-nearest-even fp32 -> bf16, packed two at a time (no NaN inputs here)
__device__ __forceinline__ uint32_t pack2_bf16(float a, float b) {
    uint32_t ua = __float_as_uint(a);
    uint32_t ub = __float_as_uint(b);
    ua += 0x7fffu + ((ua >> 16) & 1u);
    ub += 0x7fffu + ((ub >> 16) & 1u);
    return (ua >> 16) | (ub & 0xffff0000u);
}

__global__ __launch_bounds__(256) void fused_linear_pool_kernel(
    const float* __restrict__ x, const float* __restrict__ wt,
    const float* __restrict__ bias, float* __restrict__ out)
{
    __shared__ uint32_t sA[BM * LDSP / 2];   // 10240 B
    __shared__ uint32_t sB[BN * LDSP / 2];   // 10240 B

    const int tid = threadIdx.x;
    const int bx = blockIdx.x;   // N tile (0..31)
    const int by = blockIdx.y;   // M tile (0..127)

    const float* Abase = x  + (size_t)by * BM * K_DIM;
    const float* Bbase = wt + (size_t)bx * BN * K_DIM;

    const int lane = tid & 63;
    const int wave = tid >> 6;
    const int wm = wave >> 1;    // wave row (0..1) -> 64 rows
    const int wn = wave & 1;     // wave col (0..1) -> 64 cols
    const int lr = lane & 15;    // A-row / B-col / C-col within 16-frag
    const int quad = lane >> 4;  // k-quad for A/B operands; row-quad for C/D

    // staging map: thread covers 8 contiguous fp32 (32B) of one row
    const int srow  = tid >> 2;        // 0..63 (+64 on second pass)
    const int scol  = (tid & 3) * 8;   // fp32 col {0,8,16,24}
    const int swidx = (tid & 3) * 4;   // uint32 col in LDS row

    f32x4 acc[4][4] = {};

    for (int kt = 0; kt < K_DIM; kt += BK) {
        #pragma unroll
        for (int p = 0; p < 2; ++p) {
            const int r = srow + p * 64;
            const float4* ga = (const float4*)(Abase + (size_t)r * K_DIM + kt + scol);
            const float4* gb = (const float4*)(Bbase + (size_t)r * K_DIM + kt + scol);
            float4 a0 = ga[0];
            float4 a1 = ga[1];
            float4 b0 = gb[0];
            float4 b1 = gb[1];
            uint4 wa;
            wa.x = pack2_bf16(a0.x, a0.y);
            wa.y = pack2_bf16(a0.z, a0.w);
            wa.z = pack2_bf16(a1.x, a1.y);
            wa.w = pack2_bf16(a1.z, a1.w);
            *(uint4*)&sA[r * (LDSP / 2) + swidx] = wa;
            uint4 wb;
            wb.x = pack2_bf16(b0.x, b0.y);
            wb.y = pack2_bf16(b0.z, b0.w);
            wb.z = pack2_bf16(b1.x, b1.y);
            wb.w = pack2_bf16(b1.z, b1.w);
            *(uint4*)&sB[r * (LDSP / 2) + swidx] = wb;
        }
        __syncthreads();

        bf16x8 af[4], bfr[4];
        #pragma unroll
        for (int i = 0; i < 4; ++i)
            af[i] = *(const bf16x8*)((const bf16*)sA + (wm * 64 + i * 16 + lr) * LDSP + quad * 8);
        #pragma unroll
        for (int j = 0; j < 4; ++j)
            bfr[j] = *(const bf16x8*)((const bf16*)sB + (wn * 64 + j * 16 + lr) * LDSP + quad * 8);

        #pragma unroll
        for (int i = 0; i < 4; ++i)
            #pragma unroll
            for (int j = 0; j < 4; ++j)
                acc[i][j] = __builtin_amdgcn_mfma_f32_16x16x32_bf16(af[i], bfr[j], acc[i][j], 0, 0, 0);
        __syncthreads();
    }

    // ---- fused epilogue: +bias, maxpool4 along N, partial row-sum, atomic out ----
    // C/D layout: col = lane&15, row = quad*4 + reg  [m89/m91 verified]
    float bv[4];
    #pragma unroll
    for (int j = 0; j < 4; ++j)
        bv[j] = bias[bx * BN + wn * 64 + j * 16 + lr];

    #pragma unroll
    for (int i = 0; i < 4; ++i) {
        float rsum[4] = {0.f, 0.f, 0.f, 0.f};
        #pragma unroll
        for (int j = 0; j < 4; ++j) {
            #pragma unroll
            for (int r = 0; r < 4; ++r) {
                float t = acc[i][j][r] + bv[j];
                // maxpool over 4 adjacent columns (lane&3 groups; 16%4==0 so
                // pool windows never straddle a frag/lane-quad boundary)
                t = fmaxf(t, __shfl_xor(t, 1, 64));
                t = fmaxf(t, __shfl_xor(t, 2, 64));
                // sum the 4 pooled maxima of this 16-col frag
                t += __shfl_xor(t, 4, 64);
                t += __shfl_xor(t, 8, 64);
                rsum[r] += t;
            }
        }
        if (lr == 0) {  // lanes 0,16,32,48 -> one per row-quad
            const int row = by * BM + wm * 64 + i * 16 + quad * 4;
            #pragma unroll
            for (int r = 0; r < 4; ++r)
                atomicAdd(&out[row + r], rsum[r] * 0.5f);
        }
    }
}

extern "C" void kernel_launch(void* const* d_in, const int* in_sizes, int n_in,
                              void* d_out, int out_size, void* d_ws, size_t ws_size,
                              hipStream_t stream) {
    const float* x  = (const float*)d_in[0];
    const float* wt = (const float*)d_in[1];
    const float* bs = (const float*)d_in[2];
    float* out = (float*)d_out;

    // d_out is poisoned 0xAA before every timed launch; we accumulate via atomics.
    hipMemsetAsync(out, 0, (size_t)out_size * sizeof(float), stream);

    dim3 grid(N_DIM / BN, M_DIM / BM);  // 32 x 128 = 4096 blocks
    fused_linear_pool_kernel<<<grid, 256, 0, stream>>>(x, wt, bs, out);
}

// Round 2
// 304.144 us; speedup vs baseline: 1.3120x; 1.3120x over previous
//
#include <hip/hip_runtime.h>
#include <stdint.h>

#define M_DIM 16384
#define K_DIM 1024
#define N_DIM 4096
#define BM 128
#define BN 128
#define BK 32
#define LDSP 40   // fallback-path pad

typedef __bf16 bf16;
typedef __attribute__((ext_vector_type(8))) __bf16 bf16x8;
typedef __attribute__((ext_vector_type(4))) float f32x4;

// round-to-nearest-even fp32 -> bf16, packed two at a time (no NaN inputs here)
__device__ __forceinline__ uint32_t pack2_bf16(float a, float b) {
    uint32_t ua = __float_as_uint(a);
    uint32_t ub = __float_as_uint(b);
    ua += 0x7fffu + ((ua >> 16) & 1u);
    ub += 0x7fffu + ((ub >> 16) & 1u);
    return (ua >> 16) | (ub & 0xffff0000u);
}

// async global->LDS DMA, 16 B per lane. lds base MUST be wave-uniform;
// HW scatters lane i to ldsbase + i*16 (m104/m108: no per-lane lds addressing).
__device__ __forceinline__ void load_lds16(const bf16* g, bf16* l) {
    __builtin_amdgcn_global_load_lds(
        (__attribute__((address_space(1))) uint32_t*)(uintptr_t)g,
        (__attribute__((address_space(3))) uint32_t*)(uintptr_t)l,
        16, 0, 0);
}

// ---------------- fp32 -> bf16 convert pass (grid-stride-free, exact-size) ---
__global__ __launch_bounds__(256) void convert_bf16_kernel(
    const float* __restrict__ in, uint4* __restrict__ out, int n8)
{
    int i = blockIdx.x * blockDim.x + threadIdx.x;
    if (i >= n8) return;
    const float4* p = (const float4*)(in + (size_t)i * 8);
    float4 a = p[0], b = p[1];
    uint4 w;
    w.x = pack2_bf16(a.x, a.y);
    w.y = pack2_bf16(a.z, a.w);
    w.z = pack2_bf16(b.x, b.y);
    w.w = pack2_bf16(b.z, b.w);
    out[i] = w;
}

// ---------------- fast path: m97-structure bf16 GEMM + fused epilogue -------
__global__ __launch_bounds__(256) void gemm_pool_lds_kernel(
    const bf16* __restrict__ xb, const bf16* __restrict__ wb,
    const float* __restrict__ bias, float* __restrict__ out)
{
    // unpadded: required by global_load_lds lane-contiguous scatter
    __shared__ bf16 sA[BM * BK];   // 8192 B, [row][k], row stride 64 B
    __shared__ bf16 sB[BN * BK];   // 8192 B

    const int tid = threadIdx.x;
    const int bx = blockIdx.x;   // N tile
    const int by = blockIdx.y;   // M tile

    const int lane = tid & 63;
    const int wave = tid >> 6;
    const int wm = wave >> 1;
    const int wn = wave & 1;
    const int lr = lane & 15;
    const int quad = lane >> 4;

    // staging: wave w fills rows [w*32, w*32+32) of each tile, as two
    // 1024 B chunks (16 rows each). lane l -> row +l/4, kcol (l&3)*8.
    const int c0row = wave * 32;
    const int grow = lane >> 2;        // 0..15
    const int gcol = (lane & 3) * 8;   // bf16 col

    const bf16* Abase = xb + (size_t)(by * BM + c0row + grow) * K_DIM + gcol;
    const bf16* Bbase = wb + (size_t)(bx * BN + c0row + grow) * K_DIM + gcol;
    bf16* ldsA0 = sA + c0row * BK;            // wave-uniform
    bf16* ldsA1 = sA + (c0row + 16) * BK;
    bf16* ldsB0 = sB + c0row * BK;
    bf16* ldsB1 = sB + (c0row + 16) * BK;
    const size_t rowskip = (size_t)16 * K_DIM;

    f32x4 acc[4][4] = {};

    for (int kt = 0; kt < K_DIM; kt += BK) {
        load_lds16(Abase + kt, ldsA0);
        load_lds16(Abase + kt + rowskip, ldsA1);
        load_lds16(Bbase + kt, ldsB0);
        load_lds16(Bbase + kt + rowskip, ldsB1);
        __syncthreads();   // compiler emits vmcnt(0) drain before s_barrier

        bf16x8 af[4], bfr[4];
        #pragma unroll
        for (int i = 0; i < 4; ++i)
            af[i] = *(const bf16x8*)(sA + (wm * 64 + i * 16 + lr) * BK + quad * 8);
        #pragma unroll
        for (int j = 0; j < 4; ++j)
            bfr[j] = *(const bf16x8*)(sB + (wn * 64 + j * 16 + lr) * BK + quad * 8);

        #pragma unroll
        for (int i = 0; i < 4; ++i)
            #pragma unroll
            for (int j = 0; j < 4; ++j)
                acc[i][j] = __builtin_amdgcn_mfma_f32_16x16x32_bf16(af[i], bfr[j], acc[i][j], 0, 0, 0);
        __syncthreads();
    }

    // fused epilogue: +bias, maxpool4 along N, row-sum, atomic out
    // C/D layout: col = lane&15, row = quad*4 + reg  [m89/m91]
    float bv[4];
    #pragma unroll
    for (int j = 0; j < 4; ++j)
        bv[j] = bias[bx * BN + wn * 64 + j * 16 + lr];

    #pragma unroll
    for (int i = 0; i < 4; ++i) {
        float rsum[4] = {0.f, 0.f, 0.f, 0.f};
        #pragma unroll
        for (int j = 0; j < 4; ++j) {
            #pragma unroll
            for (int r = 0; r < 4; ++r) {
                float t = acc[i][j][r] + bv[j];
                t = fmaxf(t, __shfl_xor(t, 1, 64));
                t = fmaxf(t, __shfl_xor(t, 2, 64));
                t += __shfl_xor(t, 4, 64);
                t += __shfl_xor(t, 8, 64);
                rsum[r] += t;
            }
        }
        if (lr == 0) {
            const int row = by * BM + wm * 64 + i * 16 + quad * 4;
            #pragma unroll
            for (int r = 0; r < 4; ++r)
                atomicAdd(&out[row + r], rsum[r] * 0.5f);
        }
    }
}

// ---------------- fallback (round-1 kernel) if ws too small -----------------
__global__ __launch_bounds__(256) void fused_linear_pool_kernel(
    const float* __restrict__ x, const float* __restrict__ wt,
    const float* __restrict__ bias, float* __restrict__ out)
{
    __shared__ uint32_t sA[BM * LDSP / 2];
    __shared__ uint32_t sB[BN * LDSP / 2];

    const int tid = threadIdx.x;
    const int bx = blockIdx.x;
    const int by = blockIdx.y;

    const float* Abase = x  + (size_t)by * BM * K_DIM;
    const float* Bbase = wt + (size_t)bx * BN * K_DIM;

    const int lane = tid & 63;
    const int wave = tid >> 6;
    const int wm = wave >> 1;
    const int wn = wave & 1;
    const int lr = lane & 15;
    const int quad = lane >> 4;

    const int srow  = tid >> 2;
    const int scol  = (tid & 3) * 8;
    const int swidx = (tid & 3) * 4;

    f32x4 acc[4][4] = {};

    for (int kt = 0; kt < K_DIM; kt += BK) {
        #pragma unroll
        for (int p = 0; p < 2; ++p) {
            const int r = srow + p * 64;
            const float4* ga = (const float4*)(Abase + (size_t)r * K_DIM + kt + scol);
            const float4* gb = (const float4*)(Bbase + (size_t)r * K_DIM + kt + scol);
            float4 a0 = ga[0], a1 = ga[1], b0 = gb[0], b1 = gb[1];
            uint4 wa;
            wa.x = pack2_bf16(a0.x, a0.y); wa.y = pack2_bf16(a0.z, a0.w);
            wa.z = pack2_bf16(a1.x, a1.y); wa.w = pack2_bf16(a1.z, a1.w);
            *(uint4*)&sA[r * (LDSP / 2) + swidx] = wa;
            uint4 wbv;
            wbv.x = pack2_bf16(b0.x, b0.y); wbv.y = pack2_bf16(b0.z, b0.w);
            wbv.z = pack2_bf16(b1.x, b1.y); wbv.w = pack2_bf16(b1.z, b1.w);
            *(uint4*)&sB[r * (LDSP / 2) + swidx] = wbv;
        }
        __syncthreads();

        bf16x8 af[4], bfr[4];
        #pragma unroll
        for (int i = 0; i < 4; ++i)
            af[i] = *(const bf16x8*)((const bf16*)sA + (wm * 64 + i * 16 + lr) * LDSP + quad * 8);
        #pragma unroll
        for (int j = 0; j < 4; ++j)
            bfr[j] = *(const bf16x8*)((const bf16*)sB + (wn * 64 + j * 16 + lr) * LDSP + quad * 8);

        #pragma unroll
        for (int i = 0; i < 4; ++i)
            #pragma unroll
            for (int j = 0; j < 4; ++j)
                acc[i][j] = __builtin_amdgcn_mfma_f32_16x16x32_bf16(af[i], bfr[j], acc[i][j], 0, 0, 0);
        __syncthreads();
    }

    float bv[4];
    #pragma unroll
    for (int j = 0; j < 4; ++j)
        bv[j] = bias[bx * BN + wn * 64 + j * 16 + lr];

    #pragma unroll
    for (int i = 0; i < 4; ++i) {
        float rsum[4] = {0.f, 0.f, 0.f, 0.f};
        #pragma unroll
        for (int j = 0; j < 4; ++j) {
            #pragma unroll
            for (int r = 0; r < 4; ++r) {
                float t = acc[i][j][r] + bv[j];
                t = fmaxf(t, __shfl_xor(t, 1, 64));
                t = fmaxf(t, __shfl_xor(t, 2, 64));
                t += __shfl_xor(t, 4, 64);
                t += __shfl_xor(t, 8, 64);
                rsum[r] += t;
            }
        }
        if (lr == 0) {
            const int row = by * BM + wm * 64 + i * 16 + quad * 4;
            #pragma unroll
            for (int r = 0; r < 4; ++r)
                atomicAdd(&out[row + r], rsum[r] * 0.5f);
        }
    }
}

extern "C" void kernel_launch(void* const* d_in, const int* in_sizes, int n_in,
                              void* d_out, int out_size, void* d_ws, size_t ws_size,
                              hipStream_t stream) {
    const float* x  = (const float*)d_in[0];
    const float* wt = (const float*)d_in[1];
    const float* bs = (const float*)d_in[2];
    float* out = (float*)d_out;

    hipMemsetAsync(out, 0, (size_t)out_size * sizeof(float), stream);

    const size_t xe = (size_t)M_DIM * K_DIM;       // 16.78M elems
    const size_t we = (size_t)N_DIM * K_DIM;       // 4.19M elems
    const size_t need = (xe + we) * sizeof(bf16);  // ~42 MB

    dim3 grid(N_DIM / BN, M_DIM / BM);  // 32 x 128 = 4096 blocks

    if (ws_size >= need) {
        bf16* xb = (bf16*)d_ws;
        bf16* wb = xb + xe;
        convert_bf16_kernel<<<(int)(xe / 8 / 256), 256, 0, stream>>>(x, (uint4*)xb, (int)(xe / 8));
        convert_bf16_kernel<<<(int)(we / 8 / 256), 256, 0, stream>>>(wt, (uint4*)wb, (int)(we / 8));
        gemm_pool_lds_kernel<<<grid, 256, 0, stream>>>(xb, wb, bs, out);
    } else {
        fused_linear_pool_kernel<<<grid, 256, 0, stream>>>(x, wt, bs, out);
    }
}

// Round 3
// 296.239 us; speedup vs baseline: 1.3470x; 1.0267x over previous
//
#include <hip/hip_runtime.h>
#include <stdint.h>

#define M_DIM 16384
#define K_DIM 1024
#define N_DIM 4096
#define BM 128
#define BN 128
#define BK 64            // 16 K-iters; 16 KB per tile
#define KT_N (K_DIM / BK)  // 16 k-tiles per row-tile
#define LDSP 40          // fallback-path pad

typedef __bf16 bf16;
typedef __attribute__((ext_vector_type(8))) __bf16 bf16x8;
typedef __attribute__((ext_vector_type(4))) float f32x4;

// round-to-nearest-even fp32 -> bf16, packed two at a time (no NaN inputs)
__device__ __forceinline__ uint32_t pack2_bf16(float a, float b) {
    uint32_t ua = __float_as_uint(a);
    uint32_t ub = __float_as_uint(b);
    ua += 0x7fffu + ((ua >> 16) & 1u);
    ub += 0x7fffu + ((ub >> 16) & 1u);
    return (ua >> 16) | (ub & 0xffff0000u);
}

// async global->LDS DMA, 16 B/lane; lds base wave-uniform, lane i -> +i*16
__device__ __forceinline__ void load_lds16(const bf16* g, bf16* l) {
    __builtin_amdgcn_global_load_lds(
        (__attribute__((address_space(1))) uint32_t*)(uintptr_t)g,
        (__attribute__((address_space(3))) uint32_t*)(uintptr_t)l,
        16, 0, 0);
}

// ---- merged fp32->bf16 convert + tile/swizzle repack -----------------------
// Dst layout: tiles of 128 rows x BK cols, tile index = rowtile*KT_N + ktile,
// tile stored contiguously (8192 bf16). Within a tile row r, the 8 chunks of
// 8 elems are stored at position c ^ (r&7)  -> conflict-free ds_read_b128.
__global__ __launch_bounds__(256) void convert_swizzle_kernel(
    const float* __restrict__ x, const float* __restrict__ w,
    uint4* __restrict__ xsw, uint4* __restrict__ wsw, int xchunks, int wchunks)
{
    int i = blockIdx.x * 256 + threadIdx.x;      // one 8-elem chunk per thread
    const float* src;
    uint4* dst;
    int idx;
    if (i < xchunks) { src = x; dst = xsw; idx = i; }
    else             { src = w; dst = wsw; idx = i - xchunks; if (idx >= wchunks) return; }

    int e = idx << 3;                 // flat elem index (fits int)
    int m = e >> 10;                  // row (K_DIM = 1024)
    int k = e & (K_DIM - 1);
    int mt = m >> 7, r = m & 127;
    int kt = k >> 6;
    int c  = (k >> 3) & 7;            // chunk within tile row
    int tile = mt * KT_N + kt;
    int dstoff = tile * 8192 + r * 64 + ((c ^ (r & 7)) << 3);  // elems

    const float4* p = (const float4*)(src + e);
    float4 a = p[0], b = p[1];
    uint4 out;
    out.x = pack2_bf16(a.x, a.y);
    out.y = pack2_bf16(a.z, a.w);
    out.z = pack2_bf16(b.x, b.y);
    out.w = pack2_bf16(b.z, b.w);
    dst[dstoff >> 3] = out;
}

// ---- fast path: swizzled bf16 GEMM + fused maxpool/rowsum epilogue ---------
__global__ __launch_bounds__(256) void gemm_pool_sw_kernel(
    const bf16* __restrict__ xb, const bf16* __restrict__ wb,
    const float* __restrict__ bias, float* __restrict__ out)
{
    __shared__ bf16 sA[BM * BK];   // 16 KB
    __shared__ bf16 sB[BN * BK];   // 16 KB

    const int tid = threadIdx.x;
    const int bx = blockIdx.x;   // N tile
    const int by = blockIdx.y;   // M tile

    const int lane = tid & 63;
    const int wave = tid >> 6;
    const int wm = wave >> 1;
    const int wn = wave & 1;
    const int lr = lane & 15;
    const int quad = lane >> 4;

    // staging: wave w copies rows [w*32, w*32+32) of each tile = 4 KB
    // contiguous, as 4 DMA instrs of 1 KB (lane-contiguous in BOTH spaces).
    const bf16* Atile0 = xb + (size_t)(by * KT_N) * 8192 + wave * 2048 + lane * 8;
    const bf16* Btile0 = wb + (size_t)(bx * KT_N) * 8192 + wave * 2048 + lane * 8;
    bf16* ldsA = sA + wave * 2048;    // wave-uniform
    bf16* ldsB = sB + wave * 2048;

    f32x4 acc[4][4] = {};

    for (int kt = 0; kt < KT_N; ++kt) {
        const bf16* ga = Atile0 + kt * 8192;
        const bf16* gb = Btile0 + kt * 8192;
        #pragma unroll
        for (int q = 0; q < 4; ++q) {
            load_lds16(ga + q * 512, ldsA + q * 512);
            load_lds16(gb + q * 512, ldsB + q * 512);
        }
        __syncthreads();

        #pragma unroll
        for (int s = 0; s < 2; ++s) {      // two K=32 MFMA steps per tile
            bf16x8 af[4], bfr[4];
            #pragma unroll
            for (int i = 0; i < 4; ++i) {
                int row = wm * 64 + i * 16 + lr;
                int pos = (s * 4 + quad) ^ (row & 7);
                af[i] = *(const bf16x8*)(sA + row * 64 + pos * 8);
            }
            #pragma unroll
            for (int j = 0; j < 4; ++j) {
                int row = wn * 64 + j * 16 + lr;
                int pos = (s * 4 + quad) ^ (row & 7);
                bfr[j] = *(const bf16x8*)(sB + row * 64 + pos * 8);
            }
            #pragma unroll
            for (int i = 0; i < 4; ++i)
                #pragma unroll
                for (int j = 0; j < 4; ++j)
                    acc[i][j] = __builtin_amdgcn_mfma_f32_16x16x32_bf16(af[i], bfr[j], acc[i][j], 0, 0, 0);
        }
        __syncthreads();
    }

    // fused epilogue: +bias, maxpool4 along N, row-sum, atomic out
    // C/D layout: col = lane&15, row = quad*4 + reg  [m89/m91]
    float bv[4];
    #pragma unroll
    for (int j = 0; j < 4; ++j)
        bv[j] = bias[bx * BN + wn * 64 + j * 16 + lr];

    #pragma unroll
    for (int i = 0; i < 4; ++i) {
        float rs[4] = {0.f, 0.f, 0.f, 0.f};
        #pragma unroll
        for (int j = 0; j < 4; ++j) {
            #pragma unroll
            for (int r = 0; r < 4; ++r) {
                float t = acc[i][j][r] + bv[j];
                t = fmaxf(t, __shfl_xor(t, 1, 64));   // quad_perm DPP
                t = fmaxf(t, __shfl_xor(t, 2, 64));
                rs[r] += t;    // lanes of a 4-group hold identical pooled max
            }
        }
        #pragma unroll
        for (int r = 0; r < 4; ++r) {
            rs[r] += __shfl_xor(rs[r], 4, 64);
            rs[r] += __shfl_xor(rs[r], 8, 64);
        }
        if (lr == 0) {
            const int row = by * BM + wm * 64 + i * 16 + quad * 4;
            #pragma unroll
            for (int r = 0; r < 4; ++r)
                atomicAdd(&out[row + r], rs[r] * 0.5f);
        }
    }
}

// ---- fallback (round-1 kernel) if ws too small -----------------------------
__global__ __launch_bounds__(256) void fused_linear_pool_kernel(
    const float* __restrict__ x, const float* __restrict__ wt,
    const float* __restrict__ bias, float* __restrict__ out)
{
    __shared__ uint32_t sA[BM * LDSP / 2];
    __shared__ uint32_t sB[BN * LDSP / 2];

    const int tid = threadIdx.x;
    const int bx = blockIdx.x;
    const int by = blockIdx.y;

    const float* Abase = x  + (size_t)by * BM * K_DIM;
    const float* Bbase = wt + (size_t)bx * BN * K_DIM;

    const int lane = tid & 63;
    const int wave = tid >> 6;
    const int wm = wave >> 1;
    const int wn = wave & 1;
    const int lr = lane & 15;
    const int quad = lane >> 4;

    const int srow  = tid >> 2;
    const int scol  = (tid & 3) * 8;
    const int swidx = (tid & 3) * 4;

    f32x4 acc[4][4] = {};

    for (int kt = 0; kt < K_DIM; kt += 32) {
        #pragma unroll
        for (int p = 0; p < 2; ++p) {
            const int r = srow + p * 64;
            const float4* ga = (const float4*)(Abase + (size_t)r * K_DIM + kt + scol);
            const float4* gb = (const float4*)(Bbase + (size_t)r * K_DIM + kt + scol);
            float4 a0 = ga[0], a1 = ga[1], b0 = gb[0], b1 = gb[1];
            uint4 wa;
            wa.x = pack2_bf16(a0.x, a0.y); wa.y = pack2_bf16(a0.z, a0.w);
            wa.z = pack2_bf16(a1.x, a1.y); wa.w = pack2_bf16(a1.z, a1.w);
            *(uint4*)&sA[r * (LDSP / 2) + swidx] = wa;
            uint4 wbv;
            wbv.x = pack2_bf16(b0.x, b0.y); wbv.y = pack2_bf16(b0.z, b0.w);
            wbv.z = pack2_bf16(b1.x, b1.y); wbv.w = pack2_bf16(b1.z, b1.w);
            *(uint4*)&sB[r * (LDSP / 2) + swidx] = wbv;
        }
        __syncthreads();

        bf16x8 af[4], bfr[4];
        #pragma unroll
        for (int i = 0; i < 4; ++i)
            af[i] = *(const bf16x8*)((const bf16*)sA + (wm * 64 + i * 16 + lr) * LDSP + quad * 8);
        #pragma unroll
        for (int j = 0; j < 4; ++j)
            bfr[j] = *(const bf16x8*)((const bf16*)sB + (wn * 64 + j * 16 + lr) * LDSP + quad * 8);

        #pragma unroll
        for (int i = 0; i < 4; ++i)
            #pragma unroll
            for (int j = 0; j < 4; ++j)
                acc[i][j] = __builtin_amdgcn_mfma_f32_16x16x32_bf16(af[i], bfr[j], acc[i][j], 0, 0, 0);
        __syncthreads();
    }

    float bv[4];
    #pragma unroll
    for (int j = 0; j < 4; ++j)
        bv[j] = bias[bx * BN + wn * 64 + j * 16 + lr];

    #pragma unroll
    for (int i = 0; i < 4; ++i) {
        float rsum[4] = {0.f, 0.f, 0.f, 0.f};
        #pragma unroll
        for (int j = 0; j < 4; ++j) {
            #pragma unroll
            for (int r = 0; r < 4; ++r) {
                float t = acc[i][j][r] + bv[j];
                t = fmaxf(t, __shfl_xor(t, 1, 64));
                t = fmaxf(t, __shfl_xor(t, 2, 64));
                t += __shfl_xor(t, 4, 64);
                t += __shfl_xor(t, 8, 64);
                rsum[r] += t;
            }
        }
        if (lr == 0) {
            const int row = by * BM + wm * 64 + i * 16 + quad * 4;
            #pragma unroll
            for (int r = 0; r < 4; ++r)
                atomicAdd(&out[row + r], rsum[r] * 0.5f);
        }
    }
}

extern "C" void kernel_launch(void* const* d_in, const int* in_sizes, int n_in,
                              void* d_out, int out_size, void* d_ws, size_t ws_size,
                              hipStream_t stream) {
    const float* x  = (const float*)d_in[0];
    const float* wt = (const float*)d_in[1];
    const float* bs = (const float*)d_in[2];
    float* out = (float*)d_out;

    hipMemsetAsync(out, 0, (size_t)out_size * sizeof(float), stream);

    const size_t xe = (size_t)M_DIM * K_DIM;
    const size_t we = (size_t)N_DIM * K_DIM;
    const size_t need = (xe + we) * sizeof(bf16);  // ~42 MB

    dim3 grid(N_DIM / BN, M_DIM / BM);  // 32 x 128 = 4096 blocks

    if (ws_size >= need) {
        bf16* xb = (bf16*)d_ws;
        bf16* wb = xb + xe;
        const int xchunks = (int)(xe / 8);          // 2,097,152
        const int wchunks = (int)(we / 8);          //   524,288
        const int total   = xchunks + wchunks;      // 2,621,440 -> 10240 blocks
        convert_swizzle_kernel<<<(total + 255) / 256, 256, 0, stream>>>(
            x, wt, (uint4*)xb, (uint4*)wb, xchunks, wchunks);
        gemm_pool_sw_kernel<<<grid, 256, 0, stream>>>(xb, wb, bs, out);
    } else {
        fused_linear_pool_kernel<<<grid, 256, 0, stream>>>(x, wt, bs, out);
    }
}

// Round 4
// 295.498 us; speedup vs baseline: 1.3504x; 1.0025x over previous
//
#include <hip/hip_runtime.h>
#include <stdint.h>

#define M_DIM 16384
#define K_DIM 1024
#define N_DIM 4096
#define BM 128
#define BN 128
#define LDSP 40          // fallback-path pad

#define TILE_ELEMS (128 * K_DIM)      // 131072 bf16 per 128-row tile
#define SLAB_ELEMS (128 * 32)         // 4096 bf16 per (tile, s) slab
#define NSLAB_X ((M_DIM / 128) * 32)  // 4096
#define NSLAB_W ((N_DIM / 128) * 32)  // 1024

typedef __bf16 bf16;
typedef __attribute__((ext_vector_type(8))) __bf16 bf16x8;
typedef __attribute__((ext_vector_type(4))) float f32x4;

// round-to-nearest-even fp32 -> bf16, packed two at a time (no NaN inputs)
__device__ __forceinline__ uint32_t pack2_bf16(float a, float b) {
    uint32_t ua = __float_as_uint(a);
    uint32_t ub = __float_as_uint(b);
    ua += 0x7fffu + ((ua >> 16) & 1u);
    ub += 0x7fffu + ((ub >> 16) & 1u);
    return (ua >> 16) | (ub & 0xffff0000u);
}

// ---- convert fp32 -> bf16 and repack into MFMA-fragment order --------------
// Packed layout, per 128-row tile (stride TILE_ELEMS):
//   [s:32][rb:8][lane:64][j:8]   (slab = one s: SLAB_ELEMS)
// where lane = q*16 + lrow encodes the mfma_16x16x32 A/B operand mapping:
//   src row = rb*16 + lrow,  src col = s*32 + q*8 + j.
// GEMM then loads a fragment as one coalesced global_load_dwordx4 per (i,s).
// One block repacks one (tile, s) slab: 128 rows x 32 cols, via LDS transpose.
__global__ __launch_bounds__(256) void convert_pack_kernel(
    const float* __restrict__ x, const float* __restrict__ w,
    bf16* __restrict__ xp, bf16* __restrict__ wp)
{
    int slab = blockIdx.x;
    const float* src;
    bf16* dst;
    if (slab < NSLAB_X) { src = x; dst = xp; }
    else                { slab -= NSLAB_X; src = w; dst = wp; }
    const int tile = slab >> 5;
    const int s    = slab & 31;

    __shared__ uint32_t ls[128 * 16];   // 128 rows x 32 bf16 = 8 KB

    const int t = threadIdx.x;
    // phase 1: coalesced read of 16 fp32, convert, store to LDS row-major
    {
        const int r  = t >> 1;            // 0..127
        const int kh = (t & 1) * 16;      // fp32 col offset within slab
        const float4* p = (const float4*)(src + (size_t)(tile * 128 + r) * K_DIM + s * 32 + kh);
        float4 a = p[0], b = p[1], c = p[2], d = p[3];
        uint32_t* lrow = &ls[r * 16 + (kh >> 1)];
        lrow[0] = pack2_bf16(a.x, a.y);
        lrow[1] = pack2_bf16(a.z, a.w);
        lrow[2] = pack2_bf16(b.x, b.y);
        lrow[3] = pack2_bf16(b.z, b.w);
        lrow[4] = pack2_bf16(c.x, c.y);
        lrow[5] = pack2_bf16(c.z, c.w);
        lrow[6] = pack2_bf16(d.x, d.y);
        lrow[7] = pack2_bf16(d.z, d.w);
    }
    __syncthreads();
    // phase 2: emit 512 fragment chunks (16 B each), fully coalesced store
    uint4* dst4 = (uint4*)(dst + (size_t)tile * TILE_ELEMS + (size_t)s * SLAB_ELEMS);
    #pragma unroll
    for (int p = 0; p < 2; ++p) {
        const int c   = t + p * 256;      // chunk 0..511
        const int lane = c & 63;
        const int rb   = c >> 6;
        const int q    = lane >> 4;
        const int lrow = lane & 15;
        const int r    = rb * 16 + lrow;
        const uint32_t* lp = &ls[r * 16 + q * 4];
        uint4 v;
        v.x = lp[0]; v.y = lp[1]; v.z = lp[2]; v.w = lp[3];
        dst4[c] = v;
    }
}

// ---- fast path: barrier-free direct-from-global MFMA GEMM + fused epilogue -
__global__ __launch_bounds__(256) void gemm_pool_direct_kernel(
    const bf16* __restrict__ xp, const bf16* __restrict__ wp,
    const float* __restrict__ bias, float* __restrict__ out)
{
    const int bx = blockIdx.x;   // N tile
    const int by = blockIdx.y;   // M tile

    const int lane = threadIdx.x & 63;
    const int wave = threadIdx.x >> 6;
    const int wm = wave >> 1;
    const int wn = wave & 1;
    const int lr = lane & 15;
    const int quad = lane >> 4;

    // fragment chunk base for this wave/lane (rb = wm*4 + i)
    const bf16* Abase = xp + (size_t)by * TILE_ELEMS + (wm * 4) * 512 + lane * 8;
    const bf16* Bbase = wp + (size_t)bx * TILE_ELEMS + (wn * 4) * 512 + lane * 8;

    f32x4 acc[4][4] = {};

    // no LDS, no barriers: loads pipeline across iterations via vmcnt(N)
    #pragma unroll 2
    for (int s = 0; s < 32; ++s) {
        const bf16* ga = Abase + s * SLAB_ELEMS;
        const bf16* gb = Bbase + s * SLAB_ELEMS;
        bf16x8 af[4], bfr[4];
        #pragma unroll
        for (int i = 0; i < 4; ++i) af[i]  = *(const bf16x8*)(ga + i * 512);
        #pragma unroll
        for (int j = 0; j < 4; ++j) bfr[j] = *(const bf16x8*)(gb + j * 512);
        #pragma unroll
        for (int i = 0; i < 4; ++i)
            #pragma unroll
            for (int j = 0; j < 4; ++j)
                acc[i][j] = __builtin_amdgcn_mfma_f32_16x16x32_bf16(af[i], bfr[j], acc[i][j], 0, 0, 0);
    }

    // fused epilogue: +bias, maxpool4 along N, row-sum, atomic out
    // C/D layout: col = lane&15, row = quad*4 + reg  [m89/m91]
    float bv[4];
    #pragma unroll
    for (int j = 0; j < 4; ++j)
        bv[j] = bias[bx * BN + wn * 64 + j * 16 + lr];

    #pragma unroll
    for (int i = 0; i < 4; ++i) {
        float rs[4] = {0.f, 0.f, 0.f, 0.f};
        #pragma unroll
        for (int j = 0; j < 4; ++j) {
            #pragma unroll
            for (int r = 0; r < 4; ++r) {
                float t = acc[i][j][r] + bv[j];
                t = fmaxf(t, __shfl_xor(t, 1, 64));   // quad_perm DPP
                t = fmaxf(t, __shfl_xor(t, 2, 64));
                rs[r] += t;    // all 4 lanes of a pool group hold the max
            }
        }
        #pragma unroll
        for (int r = 0; r < 4; ++r) {
            rs[r] += __shfl_xor(rs[r], 4, 64);
            rs[r] += __shfl_xor(rs[r], 8, 64);
        }
        if (lr == 0) {
            const int row = by * BM + wm * 64 + i * 16 + quad * 4;
            #pragma unroll
            for (int r = 0; r < 4; ++r)
                atomicAdd(&out[row + r], rs[r] * 0.5f);
        }
    }
}

// ---- fallback (round-1 kernel) if ws too small -----------------------------
__global__ __launch_bounds__(256) void fused_linear_pool_kernel(
    const float* __restrict__ x, const float* __restrict__ wt,
    const float* __restrict__ bias, float* __restrict__ out)
{
    __shared__ uint32_t sA[BM * LDSP / 2];
    __shared__ uint32_t sB[BN * LDSP / 2];

    const int tid = threadIdx.x;
    const int bx = blockIdx.x;
    const int by = blockIdx.y;

    const float* Abase = x  + (size_t)by * BM * K_DIM;
    const float* Bbase = wt + (size_t)bx * BN * K_DIM;

    const int lane = tid & 63;
    const int wave = tid >> 6;
    const int wm = wave >> 1;
    const int wn = wave & 1;
    const int lr = lane & 15;
    const int quad = lane >> 4;

    const int srow  = tid >> 2;
    const int scol  = (tid & 3) * 8;
    const int swidx = (tid & 3) * 4;

    f32x4 acc[4][4] = {};

    for (int kt = 0; kt < K_DIM; kt += 32) {
        #pragma unroll
        for (int p = 0; p < 2; ++p) {
            const int r = srow + p * 64;
            const float4* ga = (const float4*)(Abase + (size_t)r * K_DIM + kt + scol);
            const float4* gb = (const float4*)(Bbase + (size_t)r * K_DIM + kt + scol);
            float4 a0 = ga[0], a1 = ga[1], b0 = gb[0], b1 = gb[1];
            uint4 wa;
            wa.x = pack2_bf16(a0.x, a0.y); wa.y = pack2_bf16(a0.z, a0.w);
            wa.z = pack2_bf16(a1.x, a1.y); wa.w = pack2_bf16(a1.z, a1.w);
            *(uint4*)&sA[r * (LDSP / 2) + swidx] = wa;
            uint4 wbv;
            wbv.x = pack2_bf16(b0.x, b0.y); wbv.y = pack2_bf16(b0.z, b0.w);
            wbv.z = pack2_bf16(b1.x, b1.y); wbv.w = pack2_bf16(b1.z, b1.w);
            *(uint4*)&sB[r * (LDSP / 2) + swidx] = wbv;
        }
        __syncthreads();

        bf16x8 af[4], bfr[4];
        #pragma unroll
        for (int i = 0; i < 4; ++i)
            af[i] = *(const bf16x8*)((const bf16*)sA + (wm * 64 + i * 16 + lr) * LDSP + quad * 8);
        #pragma unroll
        for (int j = 0; j < 4; ++j)
            bfr[j] = *(const bf16x8*)((const bf16*)sB + (wn * 64 + j * 16 + lr) * LDSP + quad * 8);

        #pragma unroll
        for (int i = 0; i < 4; ++i)
            #pragma unroll
            for (int j = 0; j < 4; ++j)
                acc[i][j] = __builtin_amdgcn_mfma_f32_16x16x32_bf16(af[i], bfr[j], acc[i][j], 0, 0, 0);
        __syncthreads();
    }

    float bv[4];
    #pragma unroll
    for (int j = 0; j < 4; ++j)
        bv[j] = bias[bx * BN + wn * 64 + j * 16 + lr];

    #pragma unroll
    for (int i = 0; i < 4; ++i) {
        float rsum[4] = {0.f, 0.f, 0.f, 0.f};
        #pragma unroll
        for (int j = 0; j < 4; ++j) {
            #pragma unroll
            for (int r = 0; r < 4; ++r) {
                float t = acc[i][j][r] + bv[j];
                t = fmaxf(t, __shfl_xor(t, 1, 64));
                t = fmaxf(t, __shfl_xor(t, 2, 64));
                t += __shfl_xor(t, 4, 64);
                t += __shfl_xor(t, 8, 64);
                rsum[r] += t;
            }
        }
        if (lr == 0) {
            const int row = by * BM + wm * 64 + i * 16 + quad * 4;
            #pragma unroll
            for (int r = 0; r < 4; ++r)
                atomicAdd(&out[row + r], rsum[r] * 0.5f);
        }
    }
}

extern "C" void kernel_launch(void* const* d_in, const int* in_sizes, int n_in,
                              void* d_out, int out_size, void* d_ws, size_t ws_size,
                              hipStream_t stream) {
    const float* x  = (const float*)d_in[0];
    const float* wt = (const float*)d_in[1];
    const float* bs = (const float*)d_in[2];
    float* out = (float*)d_out;

    hipMemsetAsync(out, 0, (size_t)out_size * sizeof(float), stream);

    const size_t xe = (size_t)M_DIM * K_DIM;
    const size_t we = (size_t)N_DIM * K_DIM;
    const size_t need = (xe + we) * sizeof(bf16);  // ~42 MB

    dim3 grid(N_DIM / BN, M_DIM / BM);  // 32 x 128 = 4096 blocks

    if (ws_size >= need) {
        bf16* xp = (bf16*)d_ws;
        bf16* wp = xp + xe;
        convert_pack_kernel<<<NSLAB_X + NSLAB_W, 256, 0, stream>>>(x, wt, xp, wp);
        gemm_pool_direct_kernel<<<grid, 256, 0, stream>>>(xp, wp, bs, out);
    } else {
        fused_linear_pool_kernel<<<grid, 256, 0, stream>>>(x, wt, bs, out);
    }
}

// Round 5
// 270.717 us; speedup vs baseline: 1.4740x; 1.0915x over previous
//
#include <hip/hip_runtime.h>
#include <stdint.h>

#define M_DIM 16384
#define K_DIM 1024
#define N_DIM 4096
#define BM 128
#define BN 128
#define LDSP 40          // fallback-path pad

#define TILE_ELEMS (128 * K_DIM)      // 131072 bf16 per 128-row tile
#define SLAB_ELEMS (128 * 32)         // 4096 bf16 per (tile, s) slab
#define NSLAB_X ((M_DIM / 128) * 32)  // 4096
#define NSLAB_W ((N_DIM / 128) * 32)  // 1024
#define CROW 20                        // convert LDS row stride (dwords), anti-conflict

typedef __bf16 bf16;
typedef __attribute__((ext_vector_type(8))) __bf16 bf16x8;
typedef __attribute__((ext_vector_type(4))) float f32x4;

// round-to-nearest-even fp32 -> bf16, packed two at a time (no NaN inputs)
__device__ __forceinline__ uint32_t pack2_bf16(float a, float b) {
    uint32_t ua = __float_as_uint(a);
    uint32_t ub = __float_as_uint(b);
    ua += 0x7fffu + ((ua >> 16) & 1u);
    ub += 0x7fffu + ((ub >> 16) & 1u);
    return (ua >> 16) | (ub & 0xffff0000u);
}

// ---- convert fp32 -> bf16 and repack into MFMA-fragment order --------------
// Packed layout per 128-row tile: [s:32][rb:8][lane:64][j:8], lane = q*16+lrow,
// src row = rb*16 + lrow, src col = s*32 + q*8 + j.
// LDS row stride padded to 20 dwords: phase-2 read banks (lrow*20)%32 cover
// all 32 banks over 8 rows -> 2-way alias only (free, m136).
__global__ __launch_bounds__(256) void convert_pack_kernel(
    const float* __restrict__ x, const float* __restrict__ w,
    bf16* __restrict__ xp, bf16* __restrict__ wp)
{
    int slab = blockIdx.x;
    const float* src;
    bf16* dst;
    if (slab < NSLAB_X) { src = x; dst = xp; }
    else                { slab -= NSLAB_X; src = w; dst = wp; }
    const int tile = slab >> 5;
    const int s    = slab & 31;

    __shared__ uint32_t ls[128 * CROW];   // 10 KB

    const int t = threadIdx.x;
    // phase 1: coalesced read of 16 fp32, convert, store to LDS row-major
    {
        const int r  = t >> 1;            // 0..127
        const int kh = (t & 1) * 16;      // fp32 col offset within slab
        const float4* p = (const float4*)(src + (size_t)(tile * 128 + r) * K_DIM + s * 32 + kh);
        float4 a = p[0], b = p[1], c = p[2], d = p[3];
        uint4* lp = (uint4*)&ls[r * CROW + (t & 1) * 8];
        uint4 v0, v1;
        v0.x = pack2_bf16(a.x, a.y); v0.y = pack2_bf16(a.z, a.w);
        v0.z = pack2_bf16(b.x, b.y); v0.w = pack2_bf16(b.z, b.w);
        v1.x = pack2_bf16(c.x, c.y); v1.y = pack2_bf16(c.z, c.w);
        v1.z = pack2_bf16(d.x, d.y); v1.w = pack2_bf16(d.z, d.w);
        lp[0] = v0; lp[1] = v1;
    }
    __syncthreads();
    // phase 2: emit 512 fragment chunks (16 B each), coalesced store
    uint4* dst4 = (uint4*)(dst + (size_t)tile * TILE_ELEMS + (size_t)s * SLAB_ELEMS);
    #pragma unroll
    for (int p = 0; p < 2; ++p) {
        const int c    = t + p * 256;     // chunk 0..511
        const int lane = c & 63;
        const int rb   = c >> 6;
        const int q    = lane >> 4;
        const int lrow = lane & 15;
        const int r    = rb * 16 + lrow;
        const uint4* lp = (const uint4*)&ls[r * CROW + q * 4];
        dst4[c] = lp[0];
    }
}

// ---- direct-from-global MFMA GEMM, register double-buffer, XCD-striped -----
__device__ __forceinline__ void load_frags(const bf16* ga, const bf16* gb,
                                           bf16x8* af, bf16x8* bf) {
    #pragma unroll
    for (int i = 0; i < 4; ++i) af[i] = *(const bf16x8*)(ga + i * 512);
    #pragma unroll
    for (int j = 0; j < 4; ++j) bf[j] = *(const bf16x8*)(gb + j * 512);
}

__device__ __forceinline__ void do_mfma(const bf16x8* af, const bf16x8* bf,
                                        f32x4 acc[4][4]) {
    #pragma unroll
    for (int i = 0; i < 4; ++i)
        #pragma unroll
        for (int j = 0; j < 4; ++j)
            acc[i][j] = __builtin_amdgcn_mfma_f32_16x16x32_bf16(af[i], bf[j], acc[i][j], 0, 0, 0);
}

__global__ __launch_bounds__(256) void gemm_pool_direct_kernel(
    const bf16* __restrict__ xp, const bf16* __restrict__ wp,
    const float* __restrict__ bias, float* __restrict__ out)
{
    // XCD-stripe remap: xcd = b&7 (dispatch round-robin). Each XCD owns a
    // 16-tile M-stripe (A slice 4 MB = one XCD L2); bx sweeps slowly so the
    // current B tile (256 KB) is L3/L2-hot chip-wide.
    const int b  = blockIdx.x;
    const int by = (b & 7) * 16 + ((b >> 3) & 15);
    const int bx = b >> 7;

    const int lane = threadIdx.x & 63;
    const int wave = threadIdx.x >> 6;
    const int wm = wave >> 1;
    const int wn = wave & 1;
    const int lr = lane & 15;
    const int quad = lane >> 4;

    const bf16* Abase = xp + (size_t)by * TILE_ELEMS + (wm * 4) * 512 + lane * 8;
    const bf16* Bbase = wp + (size_t)bx * TILE_ELEMS + (wn * 4) * 512 + lane * 8;

    f32x4 acc[4][4] = {};
    bf16x8 aA[4], bA[4], aB[4], bB[4];

    // register double-buffer: slab s+1 loads in flight during MFMA(s).
    // No barriers anywhere -> compiler can wait vmcnt(8) instead of 0.
    load_frags(Abase, Bbase, aA, bA);
    #pragma unroll
    for (int s = 0; s < 32; s += 2) {
        load_frags(Abase + (s + 1) * SLAB_ELEMS, Bbase + (s + 1) * SLAB_ELEMS, aB, bB);
        do_mfma(aA, bA, acc);
        if (s + 2 < 32)
            load_frags(Abase + (s + 2) * SLAB_ELEMS, Bbase + (s + 2) * SLAB_ELEMS, aA, bA);
        do_mfma(aB, bB, acc);
    }

    // fused epilogue: +bias, maxpool4 along N, row-sum, atomic out
    // C/D layout: col = lane&15, row = quad*4 + reg  [m89/m91]
    float bv[4];
    #pragma unroll
    for (int j = 0; j < 4; ++j)
        bv[j] = bias[bx * BN + wn * 64 + j * 16 + lr];

    #pragma unroll
    for (int i = 0; i < 4; ++i) {
        float rs[4] = {0.f, 0.f, 0.f, 0.f};
        #pragma unroll
        for (int j = 0; j < 4; ++j) {
            #pragma unroll
            for (int r = 0; r < 4; ++r) {
                float t = acc[i][j][r] + bv[j];
                t = fmaxf(t, __shfl_xor(t, 1, 64));   // quad_perm DPP
                t = fmaxf(t, __shfl_xor(t, 2, 64));
                rs[r] += t;    // all 4 lanes of a pool group hold the max
            }
        }
        #pragma unroll
        for (int r = 0; r < 4; ++r) {
            rs[r] += __shfl_xor(rs[r], 4, 64);
            rs[r] += __shfl_xor(rs[r], 8, 64);
        }
        if (lr == 0) {
            const int row = by * BM + wm * 64 + i * 16 + quad * 4;
            #pragma unroll
            for (int r = 0; r < 4; ++r)
                atomicAdd(&out[row + r], rs[r] * 0.5f);
        }
    }
}

// ---- fallback (round-1 kernel) if ws too small -----------------------------
__global__ __launch_bounds__(256) void fused_linear_pool_kernel(
    const float* __restrict__ x, const float* __restrict__ wt,
    const float* __restrict__ bias, float* __restrict__ out)
{
    __shared__ uint32_t sA[BM * LDSP / 2];
    __shared__ uint32_t sB[BN * LDSP / 2];

    const int tid = threadIdx.x;
    const int bx = blockIdx.x;
    const int by = blockIdx.y;

    const float* Abase = x  + (size_t)by * BM * K_DIM;
    const float* Bbase = wt + (size_t)bx * BN * K_DIM;

    const int lane = tid & 63;
    const int wave = tid >> 6;
    const int wm = wave >> 1;
    const int wn = wave & 1;
    const int lr = lane & 15;
    const int quad = lane >> 4;

    const int srow  = tid >> 2;
    const int scol  = (tid & 3) * 8;
    const int swidx = (tid & 3) * 4;

    f32x4 acc[4][4] = {};

    for (int kt = 0; kt < K_DIM; kt += 32) {
        #pragma unroll
        for (int p = 0; p < 2; ++p) {
            const int r = srow + p * 64;
            const float4* ga = (const float4*)(Abase + (size_t)r * K_DIM + kt + scol);
            const float4* gb = (const float4*)(Bbase + (size_t)r * K_DIM + kt + scol);
            float4 a0 = ga[0], a1 = ga[1], b0 = gb[0], b1 = gb[1];
            uint4 wa;
            wa.x = pack2_bf16(a0.x, a0.y); wa.y = pack2_bf16(a0.z, a0.w);
            wa.z = pack2_bf16(a1.x, a1.y); wa.w = pack2_bf16(a1.z, a1.w);
            *(uint4*)&sA[r * (LDSP / 2) + swidx] = wa;
            uint4 wbv;
            wbv.x = pack2_bf16(b0.x, b0.y); wbv.y = pack2_bf16(b0.z, b0.w);
            wbv.z = pack2_bf16(b1.x, b1.y); wbv.w = pack2_bf16(b1.z, b1.w);
            *(uint4*)&sB[r * (LDSP / 2) + swidx] = wbv;
        }
        __syncthreads();

        bf16x8 af[4], bfr[4];
        #pragma unroll
        for (int i = 0; i < 4; ++i)
            af[i] = *(const bf16x8*)((const bf16*)sA + (wm * 64 + i * 16 + lr) * LDSP + quad * 8);
        #pragma unroll
        for (int j = 0; j < 4; ++j)
            bfr[j] = *(const bf16x8*)((const bf16*)sB + (wn * 64 + j * 16 + lr) * LDSP + quad * 8);

        #pragma unroll
        for (int i = 0; i < 4; ++i)
            #pragma unroll
            for (int j = 0; j < 4; ++j)
                acc[i][j] = __builtin_amdgcn_mfma_f32_16x16x32_bf16(af[i], bfr[j], acc[i][j], 0, 0, 0);
        __syncthreads();
    }

    float bv[4];
    #pragma unroll
    for (int j = 0; j < 4; ++j)
        bv[j] = bias[bx * BN + wn * 64 + j * 16 + lr];

    #pragma unroll
    for (int i = 0; i < 4; ++i) {
        float rsum[4] = {0.f, 0.f, 0.f, 0.f};
        #pragma unroll
        for (int j = 0; j < 4; ++j) {
            #pragma unroll
            for (int r = 0; r < 4; ++r) {
                float t = acc[i][j][r] + bv[j];
                t = fmaxf(t, __shfl_xor(t, 1, 64));
                t = fmaxf(t, __shfl_xor(t, 2, 64));
                t += __shfl_xor(t, 4, 64);
                t += __shfl_xor(t, 8, 64);
                rsum[r] += t;
            }
        }
        if (lr == 0) {
            const int row = by * BM + wm * 64 + i * 16 + quad * 4;
            #pragma unroll
            for (int r = 0; r < 4; ++r)
                atomicAdd(&out[row + r], rsum[r] * 0.5f);
        }
    }
}

extern "C" void kernel_launch(void* const* d_in, const int* in_sizes, int n_in,
                              void* d_out, int out_size, void* d_ws, size_t ws_size,
                              hipStream_t stream) {
    const float* x  = (const float*)d_in[0];
    const float* wt = (const float*)d_in[1];
    const float* bs = (const float*)d_in[2];
    float* out = (float*)d_out;

    hipMemsetAsync(out, 0, (size_t)out_size * sizeof(float), stream);

    const size_t xe = (size_t)M_DIM * K_DIM;
    const size_t we = (size_t)N_DIM * K_DIM;
    const size_t need = (xe + we) * sizeof(bf16);  // ~42 MB

    if (ws_size >= need) {
        bf16* xp = (bf16*)d_ws;
        bf16* wp = xp + xe;
        convert_pack_kernel<<<NSLAB_X + NSLAB_W, 256, 0, stream>>>(x, wt, xp, wp);
        gemm_pool_direct_kernel<<<(M_DIM / BM) * (N_DIM / BN), 256, 0, stream>>>(xp, wp, bs, out);
    } else {
        dim3 grid(N_DIM / BN, M_DIM / BM);
        fused_linear_pool_kernel<<<grid, 256, 0, stream>>>(x, wt, bs, out);
    }
}

// Round 6
// 268.469 us; speedup vs baseline: 1.4864x; 1.0084x over previous
//
#include <hip/hip_runtime.h>
#include <stdint.h>

#define M_DIM 16384
#define K_DIM 1024
#define N_DIM 4096
#define BM 128
#define BN 128
#define LDSP 40          // fallback-path pad

#define TILE_ELEMS (128 * K_DIM)      // 131072 bf16 per 128-row tile
#define SLAB_ELEMS (128 * 32)         // 4096 bf16 per (tile, s) slab
#define NSLAB_X ((M_DIM / 128) * 32)  // 4096
#define NSLAB_W ((N_DIM / 128) * 32)  // 1024
#define CROW 20                        // convert LDS row stride (dwords)

typedef __bf16 bf16;
typedef __attribute__((ext_vector_type(8))) __bf16 bf16x8;
typedef __attribute__((ext_vector_type(4))) float f32x4;

// round-to-nearest-even fp32 -> bf16, packed two at a time (no NaN inputs)
__device__ __forceinline__ uint32_t pack2_bf16(float a, float b) {
    uint32_t ua = __float_as_uint(a);
    uint32_t ub = __float_as_uint(b);
    ua += 0x7fffu + ((ua >> 16) & 1u);
    ub += 0x7fffu + ((ub >> 16) & 1u);
    return (ua >> 16) | (ub & 0xffff0000u);
}

// ---- convert fp32 -> bf16 and repack into MFMA-fragment order --------------
// Packed layout per 128-row tile: [s:32][rb:8][lane:64][j:8], lane = q*16+lrow,
// src row = rb*16 + lrow, src col = s*32 + q*8 + j.
__global__ __launch_bounds__(256) void convert_pack_kernel(
    const float* __restrict__ x, const float* __restrict__ w,
    bf16* __restrict__ xp, bf16* __restrict__ wp)
{
    int slab = blockIdx.x;
    const float* src;
    bf16* dst;
    if (slab < NSLAB_X) { src = x; dst = xp; }
    else                { slab -= NSLAB_X; src = w; dst = wp; }
    const int tile = slab >> 5;
    const int s    = slab & 31;

    __shared__ uint32_t ls[128 * CROW];   // 10 KB

    const int t = threadIdx.x;
    // phase 1: coalesced read of 16 fp32, convert, store to LDS row-major
    {
        const int r  = t >> 1;            // 0..127
        const int kh = (t & 1) * 16;      // fp32 col offset within slab
        const float4* p = (const float4*)(src + (size_t)(tile * 128 + r) * K_DIM + s * 32 + kh);
        float4 a = p[0], b = p[1], c = p[2], d = p[3];
        uint4* lp = (uint4*)&ls[r * CROW + (t & 1) * 8];
        uint4 v0, v1;
        v0.x = pack2_bf16(a.x, a.y); v0.y = pack2_bf16(a.z, a.w);
        v0.z = pack2_bf16(b.x, b.y); v0.w = pack2_bf16(b.z, b.w);
        v1.x = pack2_bf16(c.x, c.y); v1.y = pack2_bf16(c.z, c.w);
        v1.z = pack2_bf16(d.x, d.y); v1.w = pack2_bf16(d.z, d.w);
        lp[0] = v0; lp[1] = v1;
    }
    __syncthreads();
    // phase 2: emit 512 fragment chunks (16 B each), coalesced store
    uint4* dst4 = (uint4*)(dst + (size_t)tile * TILE_ELEMS + (size_t)s * SLAB_ELEMS);
    #pragma unroll
    for (int p = 0; p < 2; ++p) {
        const int c    = t + p * 256;     // chunk 0..511
        const int lane = c & 63;
        const int rb   = c >> 6;
        const int q    = lane >> 4;
        const int lrow = lane & 15;
        const int r    = rb * 16 + lrow;
        const uint4* lp = (const uint4*)&ls[r * CROW + q * 4];
        dst4[c] = lp[0];
    }
}

// ---- direct-from-global MFMA GEMM, asymmetric-depth pipeline, XCD-striped --
__device__ __forceinline__ void load_set(const bf16* g, bf16x8* f) {
    #pragma unroll
    for (int i = 0; i < 4; ++i) f[i] = *(const bf16x8*)(g + i * 512);
}

__device__ __forceinline__ void do_mfma(const bf16x8* af, const bf16x8* bf,
                                        f32x4 acc[4][4]) {
    #pragma unroll
    for (int i = 0; i < 4; ++i)
        #pragma unroll
        for (int j = 0; j < 4; ++j)
            acc[i][j] = __builtin_amdgcn_mfma_f32_16x16x32_bf16(af[i], bf[j], acc[i][j], 0, 0, 0);
}

__global__ __launch_bounds__(256, 3) void gemm_pool_direct_kernel(
    const bf16* __restrict__ xp, const bf16* __restrict__ wp,
    const float* __restrict__ bias, float* __restrict__ out)
{
    // 2-phase XCD stripe map: xcd = b&7 (dispatch round-robin). Each XCD owns
    // an 8-tile A stripe (2 MB -> fits 4 MB L2 with headroom) per phase; bx
    // sweeps slowly so the active B tile is L2/L3-hot chip-wide.
    const int b     = blockIdx.x;
    const int xcd   = b & 7;
    const int o     = (b >> 3) & 7;
    const int bx    = (b >> 6) & 31;
    const int phase = b >> 11;
    const int by    = phase * 64 + xcd * 8 + o;

    const int lane = threadIdx.x & 63;
    const int wave = threadIdx.x >> 6;
    const int wm = wave >> 1;
    const int wn = wave & 1;
    const int lr = lane & 15;
    const int quad = lane >> 4;

    const bf16* Abase = xp + (size_t)by * TILE_ELEMS + (wm * 4) * 512 + lane * 8;
    const bf16* Bbase = wp + (size_t)bx * TILE_ELEMS + (wn * 4) * 512 + lane * 8;

    f32x4 acc[4][4] = {};
    bf16x8 Af[2][4];   // A: double-buffer, 1 slab ahead (L2-hit class)
    bf16x8 Bf[3][4];   // B: tri-buffer, 2 slabs ahead (L3-latency class)

    // prologue: B two slabs deep, A one
    load_set(Bbase, Bf[0]);
    load_set(Bbase + SLAB_ELEMS, Bf[1]);
    load_set(Abase, Af[0]);

    // fully unrolled: buffer indices fold to constants; no barriers anywhere,
    // so the compiler waits with fine-grained vmcnt(N), loads stay in flight.
    #pragma unroll
    for (int s = 0; s < 32; ++s) {
        if (s + 2 < 32) load_set(Bbase + (s + 2) * SLAB_ELEMS, Bf[(s + 2) % 3]);
        if (s + 1 < 32) load_set(Abase + (s + 1) * SLAB_ELEMS, Af[(s + 1) & 1]);
        do_mfma(Af[s & 1], Bf[s % 3], acc);
    }

    // fused epilogue: +bias, maxpool4 along N, row-sum, atomic out
    // C/D layout: col = lane&15, row = quad*4 + reg  [m89/m91]
    float bv[4];
    #pragma unroll
    for (int j = 0; j < 4; ++j)
        bv[j] = bias[bx * BN + wn * 64 + j * 16 + lr];

    #pragma unroll
    for (int i = 0; i < 4; ++i) {
        float rs[4] = {0.f, 0.f, 0.f, 0.f};
        #pragma unroll
        for (int j = 0; j < 4; ++j) {
            #pragma unroll
            for (int r = 0; r < 4; ++r) {
                float t = acc[i][j][r] + bv[j];
                t = fmaxf(t, __shfl_xor(t, 1, 64));   // quad_perm DPP
                t = fmaxf(t, __shfl_xor(t, 2, 64));
                rs[r] += t;    // all 4 lanes of a pool group hold the max
            }
        }
        #pragma unroll
        for (int r = 0; r < 4; ++r) {
            rs[r] += __shfl_xor(rs[r], 4, 64);
            rs[r] += __shfl_xor(rs[r], 8, 64);
        }
        if (lr == 0) {
            const int row = by * BM + wm * 64 + i * 16 + quad * 4;
            #pragma unroll
            for (int r = 0; r < 4; ++r)
                atomicAdd(&out[row + r], rs[r] * 0.5f);
        }
    }
}

// ---- fallback (round-1 kernel) if ws too small -----------------------------
__global__ __launch_bounds__(256) void fused_linear_pool_kernel(
    const float* __restrict__ x, const float* __restrict__ wt,
    const float* __restrict__ bias, float* __restrict__ out)
{
    __shared__ uint32_t sA[BM * LDSP / 2];
    __shared__ uint32_t sB[BN * LDSP / 2];

    const int tid = threadIdx.x;
    const int bx = blockIdx.x;
    const int by = blockIdx.y;

    const float* Abase = x  + (size_t)by * BM * K_DIM;
    const float* Bbase = wt + (size_t)bx * BN * K_DIM;

    const int lane = tid & 63;
    const int wave = tid >> 6;
    const int wm = wave >> 1;
    const int wn = wave & 1;
    const int lr = lane & 15;
    const int quad = lane >> 4;

    const int srow  = tid >> 2;
    const int scol  = (tid & 3) * 8;
    const int swidx = (tid & 3) * 4;

    f32x4 acc[4][4] = {};

    for (int kt = 0; kt < K_DIM; kt += 32) {
        #pragma unroll
        for (int p = 0; p < 2; ++p) {
            const int r = srow + p * 64;
            const float4* ga = (const float4*)(Abase + (size_t)r * K_DIM + kt + scol);
            const float4* gb = (const float4*)(Bbase + (size_t)r * K_DIM + kt + scol);
            float4 a0 = ga[0], a1 = ga[1], b0 = gb[0], b1 = gb[1];
            uint4 wa;
            wa.x = pack2_bf16(a0.x, a0.y); wa.y = pack2_bf16(a0.z, a0.w);
            wa.z = pack2_bf16(a1.x, a1.y); wa.w = pack2_bf16(a1.z, a1.w);
            *(uint4*)&sA[r * (LDSP / 2) + swidx] = wa;
            uint4 wbv;
            wbv.x = pack2_bf16(b0.x, b0.y); wbv.y = pack2_bf16(b0.z, b0.w);
            wbv.z = pack2_bf16(b1.x, b1.y); wbv.w = pack2_bf16(b1.z, b1.w);
            *(uint4*)&sB[r * (LDSP / 2) + swidx] = wbv;
        }
        __syncthreads();

        bf16x8 af[4], bfr[4];
        #pragma unroll
        for (int i = 0; i < 4; ++i)
            af[i] = *(const bf16x8*)((const bf16*)sA + (wm * 64 + i * 16 + lr) * LDSP + quad * 8);
        #pragma unroll
        for (int j = 0; j < 4; ++j)
            bfr[j] = *(const bf16x8*)((const bf16*)sB + (wn * 64 + j * 16 + lr) * LDSP + quad * 8);

        #pragma unroll
        for (int i = 0; i < 4; ++i)
            #pragma unroll
            for (int j = 0; j < 4; ++j)
                acc[i][j] = __builtin_amdgcn_mfma_f32_16x16x32_bf16(af[i], bfr[j], acc[i][j], 0, 0, 0);
        __syncthreads();
    }

    float bv[4];
    #pragma unroll
    for (int j = 0; j < 4; ++j)
        bv[j] = bias[bx * BN + wn * 64 + j * 16 + lr];

    #pragma unroll
    for (int i = 0; i < 4; ++i) {
        float rsum[4] = {0.f, 0.f, 0.f, 0.f};
        #pragma unroll
        for (int j = 0; j < 4; ++j) {
            #pragma unroll
            for (int r = 0; r < 4; ++r) {
                float t = acc[i][j][r] + bv[j];
                t = fmaxf(t, __shfl_xor(t, 1, 64));
                t = fmaxf(t, __shfl_xor(t, 2, 64));
                t += __shfl_xor(t, 4, 64);
                t += __shfl_xor(t, 8, 64);
                rsum[r] += t;
            }
        }
        if (lr == 0) {
            const int row = by * BM + wm * 64 + i * 16 + quad * 4;
            #pragma unroll
            for (int r = 0; r < 4; ++r)
                atomicAdd(&out[row + r], rsum[r] * 0.5f);
        }
    }
}

extern "C" void kernel_launch(void* const* d_in, const int* in_sizes, int n_in,
                              void* d_out, int out_size, void* d_ws, size_t ws_size,
                              hipStream_t stream) {
    const float* x  = (const float*)d_in[0];
    const float* wt = (const float*)d_in[1];
    const float* bs = (const float*)d_in[2];
    float* out = (float*)d_out;

    hipMemsetAsync(out, 0, (size_t)out_size * sizeof(float), stream);

    const size_t xe = (size_t)M_DIM * K_DIM;
    const size_t we = (size_t)N_DIM * K_DIM;
    const size_t need = (xe + we) * sizeof(bf16);  // ~42 MB

    if (ws_size >= need) {
        bf16* xp = (bf16*)d_ws;
        bf16* wp = xp + xe;
        convert_pack_kernel<<<NSLAB_X + NSLAB_W, 256, 0, stream>>>(x, wt, xp, wp);
        gemm_pool_direct_kernel<<<(M_DIM / BM) * (N_DIM / BN), 256, 0, stream>>>(xp, wp, bs, out);
    } else {
        dim3 grid(N_DIM / BN, M_DIM / BM);
        fused_linear_pool_kernel<<<grid, 256, 0, stream>>>(x, wt, bs, out);
    }
}